// Round 1
// baseline (50.200 us; speedup 1.0000x reference)
//
#include <hip/hip_runtime.h>
#include <hip/hip_bf16.h>

#define HW        1659      // 21*79
#define GLYPH_DIM 1536
#define NB        8         // batches per block
#define THREADS   256
#define EMB_PAD   24        // padded emb row stride (16B-aligned rows)

__device__ __forceinline__ float fast_tanh(float x) {
    float ax = fabsf(x);
    float e  = __expf(-2.0f * ax);
    float r  = (1.0f - e) / (1.0f + e);
    return copysignf(r, x);
}

__global__ __launch_bounds__(THREADS, 2) void glyphbag_kernel(
    const int* __restrict__ gchar, const int* __restrict__ gcol,
    const float* __restrict__ ctab, const float* __restrict__ ktab,
    const float* __restrict__ Wih, const float* __restrict__ Whh,
    const float* __restrict__ bih, const float* __restrict__ bhh,
    float* __restrict__ out_h, float* __restrict__ out_emb,
    float* __restrict__ out_bag)
{
    __shared__ unsigned int mask[NB][48];   // 1536 bits per batch
    __shared__ int   ids[NB][64];
    __shared__ int   lens[NB];
    __shared__ float embS[NB][64][EMB_PAD];
    __shared__ float hS[NB][32];

    const int tid = threadIdx.x;
    const int b0  = blockIdx.x * NB;

    // ---- zero bitmasks ----
    for (int w = tid; w < NB * 48; w += THREADS)
        ((unsigned int*)mask)[w] = 0u;
    __syncthreads();

    // ---- phase A: histogram (bitmap) ----
    const int4* cp = (const int4*)(gchar + (long)b0 * HW);
    const int4* kp = (const int4*)(gcol  + (long)b0 * HW);
    const int n4 = (NB * HW) / 4;   // 3318, exact
    for (int idx = tid; idx < n4; idx += THREADS) {
        int4 c = cp[idx];
        int4 k = kp[idx];
        int g = idx * 4;
        int id0 = c.x * 16 + k.x;
        int id1 = c.y * 16 + k.y;
        int id2 = c.z * 16 + k.z;
        int id3 = c.w * 16 + k.w;
        int bl0 = (g + 0) / HW;
        int bl1 = (g + 1) / HW;
        int bl2 = (g + 2) / HW;
        int bl3 = (g + 3) / HW;
        atomicOr(&mask[bl0][id0 >> 5], 1u << (id0 & 31));
        atomicOr(&mask[bl1][id1 >> 5], 1u << (id1 & 31));
        atomicOr(&mask[bl2][id2 >> 5], 1u << (id2 & 31));
        atomicOr(&mask[bl3][id3 >> 5], 1u << (id3 & 31));
    }
    __syncthreads();

    // ---- phase B: first-64 sorted unique ids per batch ----
    const int bl  = tid >> 5;   // batch group (32 lanes each, half-wave)
    const int l32 = tid & 31;
    {
        unsigned long long m = 0ull;
        if (l32 < 24)
            m = ((unsigned long long)mask[bl][2 * l32 + 1] << 32) |
                (unsigned long long)mask[bl][2 * l32];
        int cnt  = __popcll(m);
        int incl = cnt;
        #pragma unroll
        for (int d = 1; d < 32; d <<= 1) {
            int nb = __shfl_up(incl, d, 32);
            if (l32 >= d) incl += nb;
        }
        int excl  = incl - cnt;
        int total = __shfl(incl, 31, 32);
        if (l32 == 0) lens[bl] = min(total, 64);
        // sentinel prefill (same wave lockstep: these stores land before the
        // enumeration stores below in program order)
        ids[bl][l32]      = GLYPH_DIM;
        ids[bl][l32 + 32] = GLYPH_DIM;
        unsigned long long mm = m;
        int r = excl;
        while (mm != 0ull && r < 64) {
            int bit = __builtin_ctzll(mm);
            ids[bl][r] = l32 * 64 + bit;
            ++r;
            mm &= (mm - 1ull);
        }
    }
    __syncthreads();

    // ---- phase C: gather embeddings, write emb + bag ----
    for (int e = tid; e < NB * 64; e += THREADS) {
        int eb = e >> 6, r = e & 63;
        int id = ids[eb][r];
        int ch = id >> 4;                              // 1536>>4 = 96 (pad row)
        int co = (id >= GLYPH_DIM) ? 16 : (id & 15);   // pad -> row 16
        const float4* crow = (const float4*)(ctab + ch * 16);
        float4 c0 = crow[0], c1 = crow[1], c2 = crow[2], c3 = crow[3];
        float4 k0 = *(const float4*)(ktab + co * 4);
        float* ep = &embS[eb][r][0];
        *(float4*)(ep + 0)  = c0;
        *(float4*)(ep + 4)  = c1;
        *(float4*)(ep + 8)  = c2;
        *(float4*)(ep + 12) = c3;
        *(float4*)(ep + 16) = k0;
        // global emb: (b*64+r)*20 is divisible by 4 -> 16B aligned
        float* gp = out_emb + ((long)(b0 + eb) * 64 + r) * 20;
        *(float4*)(gp + 0)  = c0;
        *(float4*)(gp + 4)  = c1;
        *(float4*)(gp + 8)  = c2;
        *(float4*)(gp + 12) = c3;
        *(float4*)(gp + 16) = k0;
        float2 bg = make_float2((float)ch, (float)co);
        *(float2*)(out_bag + ((long)(b0 + eb) * 64 + r) * 2) = bg;
    }

    // ---- phase D: RNN (thread = (batch bl, hidden i)) ----
    const int i = l32;
    float wih[20], whh[32];
    #pragma unroll
    for (int j = 0; j < 20; j += 4)
        *(float4*)&wih[j] = *(const float4*)(Wih + i * 20 + j);
    #pragma unroll
    for (int k = 0; k < 32; k += 4)
        *(float4*)&whh[k] = *(const float4*)(Whh + i * 32 + k);
    const float bias = bih[i] + bhh[i];

    __syncthreads();   // embS ready

    const int len = lens[bl];
    float h = 0.0f;
    hS[bl][i] = 0.0f;   // same half-wave group writes+reads: lockstep, no barrier
    for (int t = 0; t < 64; ++t) {
        float acc = bias;
        const float* xp = &embS[bl][t][0];
        #pragma unroll
        for (int j = 0; j < 20; j += 4) {
            float4 x = *(const float4*)(xp + j);
            acc += wih[j] * x.x + wih[j + 1] * x.y + wih[j + 2] * x.z + wih[j + 3] * x.w;
        }
        #pragma unroll
        for (int k = 0; k < 32; k += 4) {
            float4 hv = *(const float4*)(&hS[bl][k]);
            acc += whh[k] * hv.x + whh[k + 1] * hv.y + whh[k + 2] * hv.z + whh[k + 3] * hv.w;
        }
        float hn = fast_tanh(acc);
        h = (t < len) ? hn : h;
        hS[bl][i] = h;
    }
    out_h[(long)(b0 + bl) * 32 + i] = h;
}

extern "C" void kernel_launch(void* const* d_in, const int* in_sizes, int n_in,
                              void* d_out, int out_size, void* d_ws, size_t ws_size,
                              hipStream_t stream) {
    const int* gchar = (const int*)d_in[0];
    const int* gcol  = (const int*)d_in[1];
    const float* ctab = (const float*)d_in[2];
    const float* ktab = (const float*)d_in[3];
    const float* Wih  = (const float*)d_in[4];
    const float* Whh  = (const float*)d_in[5];
    const float* bih  = (const float*)d_in[6];
    const float* bhh  = (const float*)d_in[7];

    const int B = in_sizes[0] / HW;          // 4096
    float* out_h   = (float*)d_out;                         // B*32
    float* out_emb = out_h + (long)B * 32;                  // B*64*20
    float* out_bag = out_emb + (long)B * 64 * 20;           // B*64*2

    const int nblk = B / NB;                 // 512
    glyphbag_kernel<<<nblk, THREADS, 0, stream>>>(
        gchar, gcol, ctab, ktab, Wih, Whh, bih, bhh, out_h, out_emb, out_bag);
}